// Round 1
// baseline (255.784 us; speedup 1.0000x reference)
//
#include <hip/hip_runtime.h>

// Problem constants (reference: ENTRY=1024, TUPLE=16, NCLS=10, BATCH=4096)
#define B_TOT   4096
#define E_SZ    1024
#define T_SZ    16
#define N_CLS   10
#define N_NEU   64                      // ENTRY / TUPLE
#define N_ADDR  65536                   // 2^TUPLE
#define RWORDS  (N_ADDR / 32)           // 2048 u32 words per neuron bitmask
#define RAMBITS_WORDS (N_CLS * N_NEU * RWORDS)   // 1,310,720 (5.24 MB)
#define SBITS_WORDS   (B_TOT * (E_SZ / 32))      // 131,072   (512 KB)

// ---- pack 0/1 float32 array into bitmask: out[t] bit j = (in[t*32+j] != 0)
__global__ __launch_bounds__(256) void pack_bits_f32(const float* __restrict__ in,
                                                     unsigned* __restrict__ out,
                                                     int nwords) {
    int tid = blockIdx.x * 256 + threadIdx.x;
    if (tid >= nwords) return;
    const float4* in4 = (const float4*)in;
    unsigned w = 0;
#pragma unroll
    for (int j = 0; j < 8; ++j) {
        float4 v = in4[(size_t)tid * 8 + j];
        w |= (v.x != 0.0f ? 1u : 0u) << (4 * j + 0);
        w |= (v.y != 0.0f ? 1u : 0u) << (4 * j + 1);
        w |= (v.z != 0.0f ? 1u : 0u) << (4 * j + 2);
        w |= (v.w != 0.0f ? 1u : 0u) << (4 * j + 3);
    }
    out[tid] = w;
}

// ---- pack 0/1 int32 array into bitmask
__global__ __launch_bounds__(256) void pack_bits_i32(const int* __restrict__ in,
                                                     unsigned* __restrict__ out,
                                                     int nwords) {
    int tid = blockIdx.x * 256 + threadIdx.x;
    if (tid >= nwords) return;
    const int4* in4 = (const int4*)in;
    unsigned w = 0;
#pragma unroll
    for (int j = 0; j < 8; ++j) {
        int4 v = in4[(size_t)tid * 8 + j];
        w |= (v.x != 0 ? 1u : 0u) << (4 * j + 0);
        w |= (v.y != 0 ? 1u : 0u) << (4 * j + 1);
        w |= (v.z != 0 ? 1u : 0u) << (4 * j + 2);
        w |= (v.w != 0 ? 1u : 0u) << (4 * j + 3);
    }
    out[tid] = w;
}

// ---- main: block = (class c, 64-batch tile), 256 threads = 4 waves.
// lane = local b (64 per tile); wave wv handles neurons [wv*16, wv*16+16).
// smp LDS padded to 33 words/row -> bank-conflict-free lane-varying reads
// with a wave-uniform word index.
__global__ __launch_bounds__(256) void wisard_main(const unsigned* __restrict__ sbits,
                                                   const int* __restrict__ tmap,
                                                   const unsigned* __restrict__ rambits,
                                                   float* __restrict__ out) {
    __shared__ unsigned smp[64 * 33];   // [b_local][word], padded
    __shared__ unsigned tm2[512];       // tuple entries, 2 packed per u32
    __shared__ int red[256];

    // XCD-aware swizzle: 640 blocks, 8 XCDs -> each XCD works ~1.25 classes
    int bid  = blockIdx.x;
    int work = (bid & 7) * 80 + (bid >> 3);
    int c     = work >> 6;   // /64
    int btile = work & 63;

    int tid = threadIdx.x;

    // stage packed sample bits for this tile's 64 b's (coalesced read,
    // 2-way LDS write aliasing = free)
    for (int i = tid; i < 64 * 32; i += 256) {
        int bl = i >> 5, w = i & 31;
        smp[bl * 33 + w] = sbits[(btile * 64 + bl) * 32 + w];
    }
    // stage tuple mapping for class c, packed as u16 pairs (entries < 1024)
    const int2* tmc2 = (const int2*)(tmap + c * 1024);
    for (int i = tid; i < 512; i += 256) {
        int2 e = tmc2[i];
        tm2[i] = (unsigned)e.x | ((unsigned)e.y << 16);
    }
    __syncthreads();

    int lane = tid & 63;
    int wv   = tid >> 6;
    unsigned row = lane * 33;
    const unsigned* ramc = rambits + ((size_t)c * N_NEU * RWORDS);

    int acc = 0;
#pragma unroll
    for (int nn = 0; nn < 16; ++nn) {
        int n = wv * 16 + nn;
        unsigned addr = 0;
#pragma unroll
        for (int i = 0; i < 8; ++i) {
            unsigned p  = tm2[n * 8 + i];          // wave-uniform -> broadcast
            unsigned e0 = p & 0xFFFFu, e1 = p >> 16;
            unsigned s0 = smp[row + (e0 >> 5)];    // conflict-free (pad 33)
            unsigned s1 = smp[row + (e1 >> 5)];
            addr = (addr << 1) | ((s0 >> (e0 & 31u)) & 1u);
            addr = (addr << 1) | ((s1 >> (e1 & 31u)) & 1u);
        }
        unsigned wrd = ramc[(n << 11) + (addr >> 5)];  // L2-resident probe
        acc += (int)((wrd >> (addr & 31u)) & 1u);
    }

    red[tid] = acc;
    __syncthreads();
    if (tid < 64) {
        int s = red[tid] + red[tid + 64] + red[tid + 128] + red[tid + 192];
        out[(btile * 64 + tid) * N_CLS + c] = (float)s;
    }
}

extern "C" void kernel_launch(void* const* d_in, const int* in_sizes, int n_in,
                              void* d_out, int out_size, void* d_ws, size_t ws_size,
                              hipStream_t stream) {
    const int*   samples = (const int*)d_in[0];    // [4096,1024] 0/1
    const int*   tmap    = (const int*)d_in[1];    // [10,1024] permutations
    const float* ram     = (const float*)d_in[2];  // [10,64,65536] 0/1

    float* out = (float*)d_out;                    // [4096,10]

    unsigned* rambits = (unsigned*)d_ws;                   // 5.24 MB
    unsigned* sbits   = rambits + RAMBITS_WORDS;           // +512 KB

    pack_bits_f32<<<RAMBITS_WORDS / 256, 256, 0, stream>>>(ram, rambits, RAMBITS_WORDS);
    pack_bits_i32<<<SBITS_WORDS / 256, 256, 0, stream>>>(samples, sbits, SBITS_WORDS);
    wisard_main<<<640, 256, 0, stream>>>(sbits, tmap, rambits, out);
}

// Round 2
// 252.386 us; speedup vs baseline: 1.0135x; 1.0135x over previous
//
#include <hip/hip_runtime.h>

// WiSARD: ENTRY=1024, TUPLE=16, NCLS=10, BATCH=4096
#define B_TOT   4096
#define E_SZ    1024
#define T_SZ    16
#define N_CLS   10
#define N_NEU   64                      // ENTRY / TUPLE
#define N_ADDR  65536                   // 2^TUPLE
#define RWORDS  (N_ADDR / 32)           // 2048 u32 words per neuron bitmask
#define RAMBITS_WORDS (N_CLS * N_NEU * RWORDS)   // 1,310,720 (5.24 MB)
#define SBITS_WORDS   (B_TOT * (E_SZ / 32))      // 131,072   (512 KB)
#define RAM_BLOCKS    (RAMBITS_WORDS / 256)      // 5120
#define SB_BLOCKS     (SBITS_WORDS / 256)        // 512

// ---- fused packer: blocks [0,5120) pack ram (f32 0/1 -> bits),
//      blocks [5120,5632) pack samples (i32 0/1 -> bits).
__global__ __launch_bounds__(256) void pack_all(const float* __restrict__ ram,
                                                const int* __restrict__ samples,
                                                unsigned* __restrict__ rambits,
                                                unsigned* __restrict__ sbits) {
    int blk = blockIdx.x;
    int tid = threadIdx.x;
    if (blk < RAM_BLOCKS) {
        int word = blk * 256 + tid;
        const float4* in4 = (const float4*)ram;
        unsigned w = 0;
#pragma unroll
        for (int j = 0; j < 8; ++j) {
            float4 v = in4[(size_t)word * 8 + j];
            w |= (v.x != 0.0f ? 1u : 0u) << (4 * j + 0);
            w |= (v.y != 0.0f ? 1u : 0u) << (4 * j + 1);
            w |= (v.z != 0.0f ? 1u : 0u) << (4 * j + 2);
            w |= (v.w != 0.0f ? 1u : 0u) << (4 * j + 3);
        }
        rambits[word] = w;
    } else {
        int word = (blk - RAM_BLOCKS) * 256 + tid;
        const int4* in4 = (const int4*)samples;
        unsigned w = 0;
#pragma unroll
        for (int j = 0; j < 8; ++j) {
            int4 v = in4[(size_t)word * 8 + j];
            w |= (v.x != 0 ? 1u : 0u) << (4 * j + 0);
            w |= (v.y != 0 ? 1u : 0u) << (4 * j + 1);
            w |= (v.z != 0 ? 1u : 0u) << (4 * j + 2);
            w |= (v.w != 0 ? 1u : 0u) << (4 * j + 3);
        }
        sbits[word] = w;
    }
}

// ---- main: block = (class c, 64-batch tile), 256 threads = 4 waves.
// lane = local b; wave wv handles neurons [wv*16, wv*16+16).
// Tuple-map entries are wave-uniform -> forced to SGPR via readfirstlane,
// so they come in on the scalar pipe (s_load), not LDS.
// smp rows padded to 33 words -> (lane+w)%32 bank mapping, 2-way = free.
__global__ __launch_bounds__(256) void wisard_main(const unsigned* __restrict__ sbits,
                                                   const int* __restrict__ tmap,
                                                   const unsigned* __restrict__ rambits,
                                                   float* __restrict__ out) {
    __shared__ unsigned smp[64 * 33];
    __shared__ int red[256];

    // XCD-aware swizzle: 640 blocks / 8 XCDs -> contiguous 80-block chunks
    int bid  = blockIdx.x;
    int work = (bid & 7) * 80 + (bid >> 3);
    int c     = work >> 6;
    int btile = work & 63;
    int tid = threadIdx.x;

    for (int i = tid; i < 64 * 32; i += 256) {
        int bl = i >> 5, w = i & 31;
        smp[bl * 33 + w] = sbits[(btile * 64 + bl) * 32 + w];
    }
    __syncthreads();

    int lane = tid & 63;
    int wvu  = __builtin_amdgcn_readfirstlane(tid >> 6);   // wave-uniform
    const int* tw = tmap + c * 1024 + wvu * 256;           // 16 neurons x 16 entries
    const unsigned* ramw = rambits + ((size_t)c << 17) + ((size_t)wvu << 15);
    unsigned row = (unsigned)(lane * 33);

    int acc = 0;
    for (int nn = 0; nn < 16; ++nn) {          // rolled: bounded live ranges
        unsigned addr = 0;
#pragma unroll
        for (int t = 0; t < 16; ++t) {
            int e = tw[nn * 16 + t];           // s_load (scalar pipe)
            unsigned s = smp[row + (unsigned)(e >> 5)];
            addr = (addr << 1) | ((s >> (e & 31)) & 1u);
        }
        unsigned wrd = ramw[(nn << 11) + (addr >> 5)];   // L2-resident probe
        acc += (int)((wrd >> (addr & 31u)) & 1u);
    }

    red[tid] = acc;
    __syncthreads();
    if (tid < 64) {
        int s = red[tid] + red[tid + 64] + red[tid + 128] + red[tid + 192];
        out[(btile * 64 + tid) * N_CLS + c] = (float)s;
    }
}

extern "C" void kernel_launch(void* const* d_in, const int* in_sizes, int n_in,
                              void* d_out, int out_size, void* d_ws, size_t ws_size,
                              hipStream_t stream) {
    const int*   samples = (const int*)d_in[0];    // [4096,1024] 0/1
    const int*   tmap    = (const int*)d_in[1];    // [10,1024] permutations
    const float* ram     = (const float*)d_in[2];  // [10,64,65536] 0/1

    float* out = (float*)d_out;                    // [4096,10]

    unsigned* rambits = (unsigned*)d_ws;                   // 5.24 MB
    unsigned* sbits   = rambits + RAMBITS_WORDS;           // +512 KB

    pack_all<<<RAM_BLOCKS + SB_BLOCKS, 256, 0, stream>>>(ram, samples, rambits, sbits);
    wisard_main<<<640, 256, 0, stream>>>(sbits, tmap, rambits, out);
}